// Round 12
// baseline (39.828 us; speedup 1.0000x reference)
//
#include <hip/hip_runtime.h>

#define FDIM 512
#define CDIM 64
#define NLEAF 1024
#define MAT (FDIM * CDIM)          /* 32768 floats per node */
#define OUT_LOGITS (NLEAF * CDIM)  /* 65536 */
#define WS_REG (NLEAF * CDIM)      /* float offset of reg partials in ws */

__device__ __forceinline__ float abs4(const float4 v) {
    return fabsf(v.x) + fabsf(v.y) + fabsf(v.z) + fabsf(v.w);
}
__device__ __forceinline__ float sq4(const float4 v) {
    return v.x * v.x + v.y * v.y + v.z * v.z + v.w * v.w;
}

// Shared-ancestor stream: this thread's 8f x 4c (c-half) tile of one node,
// 2 bursts x 4-deep (R3/R11-proven shape); FMA into all FOUR leaves' accs.
// MODE: 0 = none, 1 = L1*scale, 2 = squared (root)
template<int MODE>
__device__ __forceinline__ void stream4(const float* __restrict__ dbase,
                                        const float4 xr[4][2],
                                        float4* __restrict__ acc,
                                        float& rsum, float s)
{
#pragma unroll
    for (int h = 0; h < 2; ++h) {
        const float* q = dbase + (size_t)(4 * h) * CDIM;
        const float4 d0 = *(const float4*)(q);
        const float4 d1 = *(const float4*)(q + CDIM);
        const float4 d2 = *(const float4*)(q + 2 * CDIM);
        const float4 d3 = *(const float4*)(q + 3 * CDIM);
        if (MODE == 1) rsum = fmaf(abs4(d0) + abs4(d1) + abs4(d2) + abs4(d3), s, rsum);
        if (MODE == 2) rsum += sq4(d0) + sq4(d1) + sq4(d2) + sq4(d3);
#pragma unroll
        for (int r = 0; r < 4; ++r) {
            const float4 xv = xr[r][h];
            acc[r].x += xv.x * d0.x + xv.y * d1.x + xv.z * d2.x + xv.w * d3.x;
            acc[r].y += xv.x * d0.y + xv.y * d1.y + xv.z * d2.y + xv.w * d3.y;
            acc[r].z += xv.x * d0.z + xv.y * d1.z + xv.z * d2.z + xv.w * d3.z;
            acc[r].w += xv.x * d0.w + xv.y * d1.w + xv.z * d2.w + xv.w * d3.w;
        }
    }
}

// Leaf stream: same burst shape, FMA into acc[R] only; always reg-owner.
template<int R>
__device__ __forceinline__ void leaf1(const float* __restrict__ dbase,
                                      const float4 xr[4][2],
                                      float4* __restrict__ acc,
                                      float& rsum, float s)
{
#pragma unroll
    for (int h = 0; h < 2; ++h) {
        const float* q = dbase + (size_t)(4 * h) * CDIM;
        const float4 d0 = *(const float4*)(q);
        const float4 d1 = *(const float4*)(q + CDIM);
        const float4 d2 = *(const float4*)(q + 2 * CDIM);
        const float4 d3 = *(const float4*)(q + 3 * CDIM);
        rsum = fmaf(abs4(d0) + abs4(d1) + abs4(d2) + abs4(d3), s, rsum);
        const float4 xv = xr[R][h];
        acc[R].x += xv.x * d0.x + xv.y * d1.x + xv.z * d2.x + xv.w * d3.x;
        acc[R].y += xv.x * d0.y + xv.y * d1.y + xv.z * d2.y + xv.w * d3.y;
        acc[R].z += xv.x * d0.z + xv.y * d1.z + xv.z * d2.z + xv.w * d3.z;
        acc[R].w += xv.x * d0.w + xv.y * d1.w + xv.z * d2.w + xv.w * d3.w;
    }
}

// ---------------------------------------------------------------------------
// One block = (sibling leaf QUAD) x (c-half). 512 blocks x 512 threads,
// 2 blocks/CU, 16 waves/CU (same residency as R11). The 5 shared ancestors
// (root..d4 = common parent) are streamed once per QUAD: demand 295 MB vs
// R11's 459 MB vs R3's 786 MB. All proven invariants kept: 4-deep bursts,
// 128B wave segments, branchy ancestor loop, root->leaf phase order, XCD
// owns leaves [128k,128k+128).
// ---------------------------------------------------------------------------
__global__ __launch_bounds__(512, 2) void k_fused(const float* __restrict__ x,
                                                  const float* __restrict__ deltas,
                                                  const float* __restrict__ heights,
                                                  float* __restrict__ ws)
{
    __shared__ float red[8 * 132];   // [wave][r*32+cc], stride 132 de-banks
    __shared__ float rr[8];

    const int tid = threadIdx.x;
    const int bid = blockIdx.x;
    // XCD k owns quads [32k,32k+32) = leaves [128k,128k+128); c-halves adjacent
    const int k  = bid & 7;
    const int t  = bid >> 3;            // 0..63
    const int q  = (k << 5) | (t >> 1); // quad 0..255
    const int ch = t & 1;               // c-half
    const int l0 = 4 * q;               // first leaf of quad
    const int fg = tid >> 3;            // 0..63 (8 f each)
    const int cq = tid & 7;             // c-quad within half
    const int f0 = fg * 8;
    const int c0 = ch * 32 + cq * 4;

    // x fragments: 4 leaves x 8 f = 8 float4 (32 VGPR)
    float4 xr[4][2];
#pragma unroll
    for (int r = 0; r < 4; ++r)
#pragma unroll
        for (int j = 0; j < 2; ++j)
            xr[r][j] = *(const float4*)(x + (size_t)(l0 + r) * FDIM + f0 + 4 * j);

    float4 acc[4];
#pragma unroll
    for (int r = 0; r < 4; ++r) acc[r] = make_float4(0.f, 0.f, 0.f, 0.f);
    float rsum = 0.f;
    const size_t toff = (size_t)f0 * CDIM + c0;

    // ---- shared ancestors root -> d4 (branchy runtime loop = hoist stopper)
#pragma unroll
    for (int d = 0; d < 5; ++d) {
        const int shift = 2 * (5 - d);
        const int start = ((1 << (2 * d)) - 1) / 3;   // 0,1,5,21,85
        const int node  = start + (l0 >> shift);
        const float* dbase = deltas + (size_t)node * MAT + toff;
        const bool doReg = (l0 & ((1 << shift) - 1)) == 0;
        if (d == 0) {
            if (doReg) stream4<2>(dbase, xr, acc, rsum, 1.f);
            else       stream4<0>(dbase, xr, acc, rsum, 0.f);
        } else {
            if (doReg) {
                const int par = (node - 1) >> 2;
                const float s = 1.f / fmaxf(fabsf(heights[node] - heights[par]), 1e-7f);
                stream4<1>(dbase, xr, acc, rsum, s);
            } else {
                stream4<0>(dbase, xr, acc, rsum, 0.f);
            }
        }
    }

    // ---- the 4 leaf slabs; sched_barriers bound load hoisting
    {
        const int n5 = 341 + l0;
        const float hp = heights[85 + q];
        const float s0 = 1.f / fmaxf(fabsf(heights[n5 + 0] - hp), 1e-7f);
        leaf1<0>(deltas + (size_t)(n5 + 0) * MAT + toff, xr, acc, rsum, s0);
        __builtin_amdgcn_sched_barrier(0);
        const float s1 = 1.f / fmaxf(fabsf(heights[n5 + 1] - hp), 1e-7f);
        leaf1<1>(deltas + (size_t)(n5 + 1) * MAT + toff, xr, acc, rsum, s1);
        __builtin_amdgcn_sched_barrier(0);
        const float s2 = 1.f / fmaxf(fabsf(heights[n5 + 2] - hp), 1e-7f);
        leaf1<2>(deltas + (size_t)(n5 + 2) * MAT + toff, xr, acc, rsum, s2);
        __builtin_amdgcn_sched_barrier(0);
        const float s3 = 1.f / fmaxf(fabsf(heights[n5 + 3] - hp), 1e-7f);
        leaf1<3>(deltas + (size_t)(n5 + 3) * MAT + toff, xr, acc, rsum, s3);
    }

    // ---- reduce over the 8 fg per wave (fg spans lane bits 3,4,5)
#pragma unroll
    for (int r = 0; r < 4; ++r) {
        acc[r].x += __shfl_xor(acc[r].x, 8, 64); acc[r].x += __shfl_xor(acc[r].x, 16, 64); acc[r].x += __shfl_xor(acc[r].x, 32, 64);
        acc[r].y += __shfl_xor(acc[r].y, 8, 64); acc[r].y += __shfl_xor(acc[r].y, 16, 64); acc[r].y += __shfl_xor(acc[r].y, 32, 64);
        acc[r].z += __shfl_xor(acc[r].z, 8, 64); acc[r].z += __shfl_xor(acc[r].z, 16, 64); acc[r].z += __shfl_xor(acc[r].z, 32, 64);
        acc[r].w += __shfl_xor(acc[r].w, 8, 64); acc[r].w += __shfl_xor(acc[r].w, 16, 64); acc[r].w += __shfl_xor(acc[r].w, 32, 64);
    }

    const int w = tid >> 6, lane = tid & 63;
    if (lane < 8) {   // lane == cq
#pragma unroll
        for (int r = 0; r < 4; ++r)
            *(float4*)(red + w * 132 + r * 32 + cq * 4) = acc[r];
    }

    // ---- reg partial: full-wave butterfly -> LDS
#pragma unroll
    for (int off = 1; off < 64; off <<= 1) rsum += __shfl_xor(rsum, off, 64);
    if (lane == 0) rr[w] = rsum;
    __syncthreads();

    // ---- write the 128 complete logits this block owns (f fully reduced)
    if (tid < 128) {
        const int r = tid >> 5, cc = tid & 31;
        float v = 0.f;
#pragma unroll
        for (int w2 = 0; w2 < 8; ++w2)
            v += red[w2 * 132 + r * 32 + cc];
        ws[(size_t)(l0 + r) * CDIM + ch * 32 + cc] = v;
    }
    if (tid == 128) {
        float v = 0.f;
#pragma unroll
        for (int w2 = 0; w2 < 8; ++w2) v += rr[w2];
        ws[WS_REG + bid] = v;
    }
}

// ---------------------------------------------------------------------------
// Finish: softmax per leaf row (logits complete in ws). One wave per row.
// ---------------------------------------------------------------------------
__global__ __launch_bounds__(256) void k_finish(const float* __restrict__ ws,
                                                float* __restrict__ out)
{
    const int l = blockIdx.x * 4 + (threadIdx.x >> 6);
    const int c = threadIdx.x & 63;
    const float v = ws[(size_t)l * CDIM + c];
    float m = v;
#pragma unroll
    for (int off = 32; off > 0; off >>= 1) m = fmaxf(m, __shfl_xor(m, off, 64));
    const float e = expf(v - m);
    float s = e;
#pragma unroll
    for (int off = 32; off > 0; off >>= 1) s += __shfl_xor(s, off, 64);
    out[(size_t)l * CDIM + c] = e / s;
}

// ---------------------------------------------------------------------------
// Sum the 512 reg partials -> out[OUT_LOGITS]
// ---------------------------------------------------------------------------
__global__ __launch_bounds__(256) void k_regsum(const float* __restrict__ ws,
                                                float* __restrict__ out)
{
    __shared__ float r[4];
    const int tid = threadIdx.x;
    const float* p = ws + WS_REG;
    float v = p[tid] + p[256 + tid];
#pragma unroll
    for (int off = 1; off < 64; off <<= 1) v += __shfl_xor(v, off, 64);
    if ((tid & 63) == 0) r[tid >> 6] = v;
    __syncthreads();
    if (tid == 0) out[OUT_LOGITS] = r[0] + r[1] + r[2] + r[3];
}

extern "C" void kernel_launch(void* const* d_in, const int* in_sizes, int n_in,
                              void* d_out, int out_size, void* d_ws, size_t ws_size,
                              hipStream_t stream)
{
    const float* x       = (const float*)d_in[0];
    const float* deltas  = (const float*)d_in[1];
    const float* heights = (const float*)d_in[2];
    float* out = (float*)d_out;
    float* ws  = (float*)d_ws;

    k_fused<<<512, 512, 0, stream>>>(x, deltas, heights, ws);
    k_finish<<<256, 256, 0, stream>>>(ws, out);
    k_regsum<<<1, 256, 0, stream>>>(ws, out);
}